// Round 5
// baseline (5518.253 us; speedup 1.0000x reference)
//
#include <hip/hip_runtime.h>
#include <math.h>

// ---------------------------------------------------------------------------
// MonLipLayer forward on MI355X.  R5: dispatch-count attack.
//  - ns_mega: 9 coupled-NS iterations in ONE kernel (manual grid barrier,
//    768 co-resident blocks), replacing 18 serialized GEMM dispatches.
//  - chain_k: all 8 layers fused in ONE kernel (row-local dataflow; h/P in
//    LDS, R weights streamed from L2 as MFMA B-fragments), replacing 16
//    dispatches and all pre/h HBM round trips.
// Math identical to R3/R4 (coupled NS 9 bf16 + 2 split iters).
// GEMM convention: C = alpha * A(MxK,row) * Bt(NxK,row)^T + beta * D.
// ---------------------------------------------------------------------------

using s8v = __attribute__((ext_vector_type(8))) short;   // 8 x bf16
using f4v = __attribute__((ext_vector_type(4))) float;
typedef unsigned short ush;
typedef unsigned int uint32;

#define DEV __device__ __forceinline__

DEV float b2f(ush u){ union{unsigned int i; float f;} v; v.i = ((unsigned int)u)<<16; return v.f; }
DEV ush f2b(float f){
  union{float f; unsigned int i;} v; v.f = f;
  unsigned int u = v.i;
  return (ush)((u + 0x7fffu + ((u>>16)&1u)) >> 16);
}

typedef __attribute__((address_space(1))) void gvoid;
typedef __attribute__((address_space(3))) void lvoid;
DEV void gload16(const void* g, void* l){
  __builtin_amdgcn_global_load_lds((gvoid*)g, (lvoid*)l, 16, 0, 0);
}

DEV void st16(ush* dst, const ush* a){
  *(int4*)dst = *(const int4*)a; *(int4*)(dst+8) = *(const int4*)(a+8);
}

struct GA {
  const ush *A0h, *A0l; long lda0;
  const ush *A1h, *A1l; long lda1; int ksplit;
  const ush *Bh, *Bl; long ldb;
  int K, M, N;
  float alpha, beta;
  long sA, sB, sO, sD;
  void *o0,*o1,*o2,*o3,*o4;
  const void *e0,*e1;
  long ldo0, ldo1, ldE;
};

enum { E_F32=0, E_BF16=1, E_SPLIT=3, E_QW=4, E_OUT=7 };

template<int BM, int BN, int EPI, bool SPLIT, bool TRX>
__global__ __launch_bounds__(256) void gemm_k(GA gq, GA gr, int zsplit)
{
  __shared__ ush sAh[BM*32];
  __shared__ ush sBh[BN*32];
  __shared__ ush sAl[SPLIT ? BM*32 : 8];
  __shared__ ush sBl[SPLIT ? BN*32 : 8];
  __shared__ uint32 tb[TRX ? 64*65 : 8];

  GA g; int bz;
  if ((int)blockIdx.z < zsplit){ g = gq; bz = blockIdx.z; }
  else                         { g = gr; bz = blockIdx.z - zsplit; }

  // supertile swizzle: groups of 8 block-rows, column-major inside a group
  const int gx = gridDim.x, gy = gridDim.y;
  const int lin = blockIdx.y*gx + blockIdx.x;
  const int per = gx*8;
  const int grp = lin / per;
  const int rem = lin - grp*per;
  int gh = gy - grp*8; if (gh > 8) gh = 8;
  const int by = grp*8 + rem % gh;
  const int bx = rem / gh;
  const int m0 = by * BM;
  const int n0 = bx * BN;
  if (m0 >= g.M || n0 >= g.N) return;

  const int t = threadIdx.x;
  const int lane = t & 63;
  const int wave = t >> 6;
  const int wm = (wave >> 1) * (BM/2);
  const int wn = (wave & 1) * (BN/2);
  constexpr int MT = BM/32;
  constexpr int NT = BN/32;

  const ush* Ah  = g.A0h + (long)bz*g.sA;
  const ush* Alp = SPLIT ? g.A0l + (long)bz*g.sA : nullptr;
  const ush* Bhp = g.Bh  + (long)bz*g.sB;
  const ush* Blp = SPLIT ? g.Bl  + (long)bz*g.sB : nullptr;

  f4v acc[MT][NT];
  #pragma unroll
  for (int i=0;i<MT;i++)
    #pragma unroll
    for (int j=0;j<NT;j++) acc[i][j] = f4v{0.f,0.f,0.f,0.f};

  const int sr  = lane >> 2;
  const int scg = lane & 3;

  for (int k0 = 0; k0 < g.K; k0 += 32) {
    __syncthreads();
    #pragma unroll
    for (int p = 0; p < BM/64; ++p) {
      const int lr = wave*16 + sr + p*64;
      const int gc = scg ^ ((lr>>1)&3);
      const int kc = k0 + gc*8;
      long aoff; const ush* gp;
      if (kc < g.ksplit){ aoff = (long)(m0+lr)*g.lda0 + kc;               gp = Ah + aoff; }
      else              { aoff = (long)(m0+lr)*g.lda1 + (kc - g.ksplit);  gp = g.A1h + aoff; }
      gload16(gp, &sAh[(wave*16 + p*64)*32]);
      if (SPLIT) gload16(Alp + aoff, &sAl[(wave*16 + p*64)*32]);
    }
    #pragma unroll
    for (int p = 0; p < BN/64; ++p) {
      const int lr = wave*16 + sr + p*64;
      const int gc = scg ^ ((lr>>1)&3);
      const long boff = (long)(n0+lr)*g.ldb + k0 + gc*8;
      gload16(Bhp + boff, &sBh[(wave*16 + p*64)*32]);
      if (SPLIT) gload16(Blp + boff, &sBl[(wave*16 + p*64)*32]);
    }
    __syncthreads();

    const int fr = lane & 15;
    const int cc = lane >> 4;
    s8v af[MT], bf_[NT];
    #pragma unroll
    for (int i=0;i<MT;i++){ const int row = wm + i*16 + fr;
      af[i] = *(const s8v*)(&sAh[row*32 + ((cc ^ ((row>>1)&3))<<3)]); }
    #pragma unroll
    for (int j=0;j<NT;j++){ const int row = wn + j*16 + fr;
      bf_[j] = *(const s8v*)(&sBh[row*32 + ((cc ^ ((row>>1)&3))<<3)]); }
    #pragma unroll
    for (int i=0;i<MT;i++)
      #pragma unroll
      for (int j=0;j<NT;j++)
        acc[i][j] = __builtin_amdgcn_mfma_f32_16x16x32_bf16(af[i], bf_[j], acc[i][j], 0,0,0);
    if (SPLIT) {
      s8v al2[MT], bl2[NT];
      #pragma unroll
      for (int j=0;j<NT;j++){ const int row = wn + j*16 + fr;
        bl2[j] = *(const s8v*)(&sBl[row*32 + ((cc ^ ((row>>1)&3))<<3)]); }
      #pragma unroll
      for (int i=0;i<MT;i++){ const int row = wm + i*16 + fr;
        al2[i] = *(const s8v*)(&sAl[row*32 + ((cc ^ ((row>>1)&3))<<3)]); }
      #pragma unroll
      for (int i=0;i<MT;i++)
        #pragma unroll
        for (int j=0;j<NT;j++)
          acc[i][j] = __builtin_amdgcn_mfma_f32_16x16x32_bf16(af[i], bl2[j], acc[i][j], 0,0,0);
      #pragma unroll
      for (int i=0;i<MT;i++)
        #pragma unroll
        for (int j=0;j<NT;j++)
          acc[i][j] = __builtin_amdgcn_mfma_f32_16x16x32_bf16(al2[i], bf_[j], acc[i][j], 0,0,0);
    }
  }

  #pragma unroll
  for (int i=0;i<MT;i++)
    #pragma unroll
    for (int j=0;j<NT;j++)
      #pragma unroll
      for (int r=0;r<4;r++) {
        const int lrow = wm + i*16 + ((lane>>4)<<2) + r;
        const int lcol = wn + j*16 + (lane & 15);
        const int grow = m0 + lrow;
        const int gcol = n0 + lcol;
        float v = g.alpha * acc[i][j][r];
        if constexpr (EPI == E_F32) {
          if (g.e0) v += g.beta * ((const float*)g.e0)[(long)bz*g.sD + (long)grow*g.ldo0 + gcol];
          ((float*)g.o0)[(long)bz*g.sO + (long)grow*g.ldo0 + gcol] = v;
        } else if constexpr (EPI == E_BF16) {
          if (g.e0) v += g.beta * b2f(((const ush*)g.e0)[(long)bz*g.sD + (long)grow*g.ldo0 + gcol]);
          ((ush*)g.o0)[(long)bz*g.sO + (long)grow*g.ldo0 + gcol] = f2b(v);
        } else if constexpr (EPI == E_SPLIT) {
          if (g.e0) v += g.beta * ((const float*)g.e0)[(long)bz*g.sD + (long)grow*g.ldo0 + gcol];
          if (g.o0) ((float*)g.o0)[(long)bz*g.sO + (long)grow*g.ldo0 + gcol] = v;
          ush hv = f2b(v);
          ush lv = f2b(v - b2f(hv));
          ((ush*)g.o1)[(long)bz*g.sO + (long)grow*g.ldo0 + gcol] = hv;
          ((ush*)g.o2)[(long)bz*g.sO + (long)grow*g.ldo0 + gcol] = lv;
          if (TRX) tb[lrow*65 + lcol] = (uint32)hv | ((uint32)lv<<16);
        } else if constexpr (EPI == E_QW) {
          ush hv = f2b(v);
          ((ush*)g.o0)[(long)bz*g.sO + (long)grow*g.ldo0 + gcol] = hv;
          tb[lrow*65 + lcol] = hv;
        } else if constexpr (EPI == E_OUT) {
          float o = 0.5f*(10.1f*((const float*)g.e0)[(long)grow*1024 + gcol] + v)
                  + ((const float*)g.e1)[gcol];
          ((float*)g.o0)[(long)grow*1024 + gcol] = o;
        }
      }

  if constexpr (TRX) {
    __syncthreads();
    const int tr  = t >> 2;
    const int seg = t & 3;
    uint32 vals[16];
    #pragma unroll
    for (int u=0;u<16;u++) vals[u] = tb[(seg*16+u)*65 + tr];
    ush hb[16] __attribute__((aligned(16)));
    ush lb[16] __attribute__((aligned(16)));
    #pragma unroll
    for (int u=0;u<16;u++){ hb[u] = (ush)(vals[u]&0xffffu); lb[u] = (ush)(vals[u]>>16); }
    const long bT = (long)bz*g.sO + (long)(n0+tr)*g.ldo1 + m0 + seg*16;
    if constexpr (EPI == E_SPLIT) {
      if (g.o3) { st16((ush*)g.o3 + bT, hb); st16((ush*)g.o4 + bT, lb); }
    } else if constexpr (EPI == E_QW) {
      st16((ush*)g.o1 + bT, hb);
    }
  }
}

// ----------------------------- NS mega-kernel ------------------------------

DEV void gbar(int* bar){
  __syncthreads();
  if (threadIdx.x==0){
    __threadfence();
    int my = __hip_atomic_load(bar+1, __ATOMIC_ACQUIRE, __HIP_MEMORY_SCOPE_AGENT);
    if (__hip_atomic_fetch_add(bar, 1, __ATOMIC_ACQ_REL, __HIP_MEMORY_SCOPE_AGENT) == 767){
      __hip_atomic_store(bar, 0, __ATOMIC_RELAXED, __HIP_MEMORY_SCOPE_AGENT);
      __hip_atomic_fetch_add(bar+1, 1, __ATOMIC_ACQ_REL, __HIP_MEMORY_SCOPE_AGENT);
    } else {
      while (__hip_atomic_load(bar+1, __ATOMIC_ACQUIRE, __HIP_MEMORY_SCOPE_AGENT) == my)
        __builtin_amdgcn_s_sleep(2);
    }
    __threadfence();
  }
  __syncthreads();
}

struct NSA {
  const ush *Mh, *MTh;
  ush *XA, *XTA, *XB, *XTB, *Y;
  float *Xf; ush *Xl, *XTl;
  const float* cvl;
  int* bar;
};

// one 64x64-tile GEMM pass.  UPD=false: C = f2b(acc) (Y pass).
// UPD=true:  Xn = 2*X2 - acc, + transposed write via tb.
template<bool UPD>
DEV void ns_pass(const ush* A, const ush* Bt, ush* C, ush* CT, const ush* X2,
                 long base, int ld, int KK, int r0, int c0,
                 ush* sAh, ush* sBh, uint32* tb, int lane, int wave, int t)
{
  const int wm=(wave>>1)*32, wn=(wave&1)*32;
  f4v acc[2][2];
  #pragma unroll
  for(int i=0;i<2;i++)
    #pragma unroll
    for(int j=0;j<2;j++) acc[i][j]=f4v{0.f,0.f,0.f,0.f};
  const int sr=lane>>2, scg=lane&3;
  for (int k0=0;k0<KK;k0+=32){
    __syncthreads();
    {
      const int lr = wave*16 + sr;
      const int gc = scg ^ ((lr>>1)&3);
      gload16(A + base + (long)(r0+lr)*ld + k0 + gc*8, &sAh[(wave*16)*32]);
      gload16(Bt + base + (long)(c0+lr)*ld + k0 + gc*8, &sBh[(wave*16)*32]);
    }
    __syncthreads();
    const int fr=lane&15, cc=lane>>4;
    s8v af[2], bf_[2];
    #pragma unroll
    for(int i=0;i<2;i++){ const int row=wm+i*16+fr;
      af[i] = *(const s8v*)(&sAh[row*32 + ((cc ^ ((row>>1)&3))<<3)]); }
    #pragma unroll
    for(int j=0;j<2;j++){ const int row=wn+j*16+fr;
      bf_[j] = *(const s8v*)(&sBh[row*32 + ((cc ^ ((row>>1)&3))<<3)]); }
    #pragma unroll
    for(int i=0;i<2;i++)
      #pragma unroll
      for(int j=0;j<2;j++)
        acc[i][j] = __builtin_amdgcn_mfma_f32_16x16x32_bf16(af[i], bf_[j], acc[i][j], 0,0,0);
  }
  #pragma unroll
  for(int i=0;i<2;i++)
    #pragma unroll
    for(int j=0;j<2;j++)
      #pragma unroll
      for(int r=0;r<4;r++){
        const int lrow = wm + i*16 + ((lane>>4)<<2) + r;
        const int lcol = wn + j*16 + (lane&15);
        const long idx = base + (long)(r0+lrow)*ld + c0 + lcol;
        if constexpr (!UPD){
          C[idx] = f2b(acc[i][j][r]);
        } else {
          ush hv = f2b(2.f*b2f(X2[idx]) - acc[i][j][r]);
          C[idx] = hv;
          tb[lrow*65 + lcol] = hv;
        }
      }
  if constexpr (UPD){
    __syncthreads();
    const int tr=t>>2, seg=t&3;
    ush hh[16] __attribute__((aligned(16)));
    #pragma unroll
    for(int u=0;u<16;u++) hh[u] = (ush)tb[(seg*16+u)*65 + tr];
    st16(CT + base + (long)(c0+tr)*ld + r0 + seg*16, hh);
  }
}

__global__ __launch_bounds__(256) void ns_mega(NSA a)
{
  __shared__ ush sAh[64*32];
  __shared__ ush sBh[64*32];
  __shared__ uint32 tb[64*65];
  const long ROFF=1048576l, RS=262144l;
  const int b = blockIdx.x;
  int bz, r0, c0, ld, KK; long base;
  if (b < 256){ bz=0; r0=(b>>4)<<6; c0=(b&15)<<6; base=0; ld=1024; KK=1024; }
  else { int q=b-256; bz=1+(q>>6); r0=((q>>3)&7)<<6; c0=(q&7)<<6;
         base=ROFF+(long)(bz-1)*RS; ld=512; KK=512; }
  const int t = threadIdx.x, lane=t&63, wave=t>>6;

  // initX: X0 = c*M^T (copy MTh), X0^T = c*M
  {
    const float c = a.cvl[bz];
    const int rr = t>>2, cs=(t&3)*16;
    const long idx = base + (long)(r0+rr)*ld + c0+cs;
    ush hh[16] __attribute__((aligned(16)));
    #pragma unroll
    for(int u=0;u<16;u++) hh[u]=f2b(c*b2f(a.MTh[idx+u]));
    st16(a.XA+idx, hh);
    #pragma unroll
    for(int u=0;u<16;u++) hh[u]=f2b(c*b2f(a.Mh[idx+u]));
    st16(a.XTA+idx, hh);
  }
  gbar(a.bar);

  ush *Xc=a.XA, *XTc=a.XTA, *Xn=a.XB, *XTn=a.XTB;
  for (int it=0; it<9; ++it){
    // Y = (M X)^T  : A=XT, Bt=M
    ns_pass<false>(XTc, a.Mh, a.Y, nullptr, nullptr, base, ld, KK, r0, c0, sAh,sBh,tb, lane,wave,t);
    gbar(a.bar);
    // X' = 2X - X*Y^T : A=X, Bt=Y
    ns_pass<true>(Xc, a.Y, Xn, XTn, Xc, base, ld, KK, r0, c0, sAh,sBh,tb, lane,wave,t);
    gbar(a.bar);
    ush* tmp;
    tmp=Xc; Xc=Xn; Xn=tmp;
    tmp=XTc; XTc=XTn; XTn=tmp;
  }
  // promote final X (in Xc == XB after 9 iters)
  {
    const int rr=t>>2, cs=(t&3)*16;
    const long idx = base + (long)(r0+rr)*ld + c0+cs;
    #pragma unroll
    for(int u=0;u<16;u++){ a.Xf[idx+u]=b2f(Xc[idx+u]); a.Xl[idx+u]=0; a.XTl[idx+u]=0; }
  }
}

// --------------------------- fused 8-layer chain ---------------------------
// Row-local: each block owns 32 batch rows; h and P live in LDS (XOR-chunk
// swizzled, 32x512 each = 64KB); R weights read as B-fragments from L2.

__global__ __launch_bounds__(512) void chain_k(const ush* __restrict__ xh,
    const ush* __restrict__ RK, const ush* __restrict__ RKT,
    const float* __restrict__ bp, ush* __restrict__ yh)
{
  __shared__ ush sH[32*512];
  __shared__ ush sP[32*512];
  const float SQ2 = 1.41421356237f;
  const int t=threadIdx.x, lane=t&63, w=t>>6;
  const int fr=lane&15, cc=lane>>4;
  const int m0g = blockIdx.x*32;

  for (int k=0;k<8;++k){
    const int K1 = (k==0)?512:1024;
    const ush* B1 = (k==0)? RKT : RK + (long)k*524288;
    const long ldb1 = (k==0)?512:1024;
    // ---- GEMM1: P = relu(sqrt2 * [xk|h] @ B1^T + b_k) ----
    f4v a1[2][4];
    #pragma unroll
    for(int i=0;i<2;i++)
      #pragma unroll
      for(int j=0;j<4;j++) a1[i][j]=f4v{0.f,0.f,0.f,0.f};
    for (int k0=0;k0<K1;k0+=32){
      s8v af[2];
      if (k0 < 512){
        #pragma unroll
        for(int i=0;i<2;i++){
          const int row = i*16+fr;
          af[i] = *(const s8v*)(xh + (long)(m0g+row)*4096 + k*512 + k0 + cc*8);
        }
      } else {
        #pragma unroll
        for(int i=0;i<2;i++){
          const int row = i*16+fr;
          const int l = ((k0-512)>>3) + cc;
          af[i] = *(const s8v*)(&sH[row*512 + ((l ^ (row&7))<<3)]);
        }
      }
      s8v bfr[4];
      #pragma unroll
      for(int j=0;j<4;j++){
        const int n = w*64 + j*16 + fr;
        bfr[j] = *(const s8v*)(B1 + (long)n*ldb1 + k0 + cc*8);
      }
      #pragma unroll
      for(int i=0;i<2;i++)
        #pragma unroll
        for(int j=0;j<4;j++)
          a1[i][j] = __builtin_amdgcn_mfma_f32_16x16x32_bf16(af[i], bfr[j], a1[i][j], 0,0,0);
    }
    #pragma unroll
    for(int j=0;j<4;j++){
      const int col = w*64 + j*16 + fr;
      const float bb = bp[k*512 + col];
      #pragma unroll
      for(int i=0;i<2;i++)
        #pragma unroll
        for(int r=0;r<4;r++){
          const int row = i*16 + cc*4 + r;
          float v = SQ2*a1[i][j][r] + bb;
          v = v>0.f? v:0.f;
          sP[row*512 + (((col>>3) ^ (row&7))<<3) + (col&7)] = f2b(v);
        }
    }
    __syncthreads();
    // ---- GEMM2: G = sqrt2 * P @ B2^T ; h' = G[:,:512]-xk ; y = h - G[:,512:]
    const int N2 = (k==0)?512:1024;
    const ush* B2 = (k==0)? RK : RKT + (long)k*524288;
    const long ldb2 = (k==0)?1024:512;
    const int wc0 = w*128;
    const bool active = (wc0 < N2);
    f4v a2[2][8];
    if (active){
      #pragma unroll
      for(int i=0;i<2;i++)
        #pragma unroll
        for(int j=0;j<8;j++) a2[i][j]=f4v{0.f,0.f,0.f,0.f};
      for (int k0=0;k0<512;k0+=32){
        s8v af[2];
        #pragma unroll
        for(int i=0;i<2;i++){
          const int row = i*16+fr;
          const int l = (k0>>3) + cc;
          af[i] = *(const s8v*)(&sP[row*512 + ((l ^ (row&7))<<3)]);
        }
        s8v bfr[8];
        #pragma unroll
        for(int j=0;j<8;j++){
          const int n = wc0 + j*16 + fr;
          bfr[j] = *(const s8v*)(B2 + (long)n*ldb2 + k0 + cc*8);
        }
        #pragma unroll
        for(int i=0;i<2;i++)
          #pragma unroll
          for(int j=0;j<8;j++)
            a2[i][j] = __builtin_amdgcn_mfma_f32_16x16x32_bf16(af[i], bfr[j], a2[i][j], 0,0,0);
      }
      #pragma unroll
      for(int i=0;i<2;i++)
        #pragma unroll
        for(int j=0;j<8;j++)
          #pragma unroll
          for(int r=0;r<4;r++){
            const int lrow = i*16 + cc*4 + r;
            const int col = wc0 + j*16 + fr;
            const float g = SQ2*a2[i][j][r];
            if (col < 512){
              float xv = b2f(xh[(long)(m0g+lrow)*4096 + k*512 + col]);
              float hv = g - xv;
              if (k==7) yh[(long)(m0g+lrow)*4096 + 3584 + col] = f2b(hv);
              else a2[i][j][r] = hv;       // hold h' in regs until barrier
            } else {
              const int c2 = col-512;
              float ho = b2f(sH[lrow*512 + (((c2>>3) ^ (lrow&7))<<3) + (c2&7)]);
              yh[(long)(m0g+lrow)*4096 + (long)(k-1)*512 + c2] = f2b(ho - g);
            }
          }
    }
    __syncthreads();          // all reads of sH (y, GEMM1) complete
    if (active && k<7 && wc0 < 512){
      #pragma unroll
      for(int i=0;i<2;i++)
        #pragma unroll
        for(int j=0;j<8;j++)
          #pragma unroll
          for(int r=0;r<4;r++){
            const int lrow = i*16 + cc*4 + r;
            const int col = wc0 + j*16 + fr;
            sH[lrow*512 + (((col>>3) ^ (lrow&7))<<3) + (col&7)] = f2b(a2[i][j][r]);
          }
    }
    __syncthreads();
  }
}

// ------------------------------ small kernels ------------------------------

__global__ __launch_bounds__(256) void k_norms(const float* __restrict__ Fq,
    const float* __restrict__ Fr0, const float* __restrict__ Frr, float* s2){
  const int y = blockIdx.y;
  const float* p; long cnt;
  if (y==0){ p=Fq; cnt=4194304l; }
  else if (y==1){ p=Fr0; cnt=262144l; }
  else { p=Frr + (long)(y-2)*524288; cnt=524288l; }
  float s = 0.f;
  for (long i = (long)blockIdx.x*256 + threadIdx.x; i < cnt; i += (long)gridDim.x*256){
    float v = p[i]; s += v*v;
  }
  #pragma unroll
  for (int o=32;o>0;o>>=1) s += __shfl_down(s, o, 64);
  __shared__ float red[4];
  if ((threadIdx.x & 63)==0) red[threadIdx.x>>6] = s;
  __syncthreads();
  if (threadIdx.x==0) atomicAdd(&s2[y], red[0]+red[1]+red[2]+red[3]);
}

__global__ void k_scales(const float* s2, const float* fq, const float* fr, float* sc){
  int t = threadIdx.x;
  if (t < 9){
    float v = (t==0)? fq[0] : fr[t-1];
    sc[t] = v / (sqrtf(s2[t]) + 1e-5f);
  }
}

__global__ __launch_bounds__(256) void k_buildT(const float* __restrict__ Fq,
    const float* __restrict__ Frr, const float* sc,
    ush* Vh, ush* Vl, ush* Vth, ush* Vtl,
    ush* Wrh, ush* Wrl, ush* WrTh, ush* WrTl){
  __shared__ uint32 tb[64*65];
  const int z = blockIdx.z;
  const int r = threadIdx.x >> 2;
  const int cs = (threadIdx.x & 3)*16;
  ush hh[16] __attribute__((aligned(16)));
  ush ll[16] __attribute__((aligned(16)));
  if (z==0){
    const long r0 = (long)blockIdx.y*64, c0 = (long)blockIdx.x*64;
    const float s = sc[0];
    const float* src = &Fq[(1024+r0+r)*1024 + c0 + cs];
    #pragma unroll
    for (int u=0;u<16;u++){
      float v = s*src[u];
      ush h = f2b(v); ush l = f2b(v - b2f(h));
      hh[u]=h; ll[u]=l;
      tb[r*65 + cs + u] = (uint32)h | ((uint32)l<<16);
    }
    st16(&Vh[(r0+r)*1024 + c0 + cs], hh);
    st16(&Vl[(r0+r)*1024 + c0 + cs], ll);
    __syncthreads();
    const int tr = threadIdx.x>>2, seg = threadIdx.x&3;
    #pragma unroll
    for (int u=0;u<16;u++){
      uint32 v = tb[(seg*16+u)*65 + tr];
      hh[u]=(ush)(v&0xffffu); ll[u]=(ush)(v>>16);
    }
    st16(&Vth[(c0+tr)*3072 + r0 + seg*16], hh);
    st16(&Vtl[(c0+tr)*3072 + r0 + seg*16], ll);
  } else {
    if (blockIdx.x>=8 || blockIdx.y>=8) return;
    const int k = z-1;
    const long r0 = (long)blockIdx.y*64, c0 = (long)blockIdx.x*64;
    const float s = sc[2+k];
    const float* src = &Frr[(long)k*524288 + (r0+r)*1024 + 512 + c0 + cs];
    #pragma unroll
    for (int u=0;u<16;u++){
      float v = s*src[u];
      ush h = f2b(v); ush l = f2b(v - b2f(h));
      hh[u]=h; ll[u]=l;
      tb[r*65 + cs + u] = (uint32)h | ((uint32)l<<16);
    }
    st16(&Wrh[(long)k*262144 + (r0+r)*512 + c0 + cs], hh);
    st16(&Wrl[(long)k*262144 + (r0+r)*512 + c0 + cs], ll);
    __syncthreads();
    const int tr = threadIdx.x>>2, seg = threadIdx.x&3;
    #pragma unroll
    for (int u=0;u<16;u++){
      uint32 v = tb[(seg*16+u)*65 + tr];
      hh[u]=(ush)(v&0xffffu); ll[u]=(ush)(v>>16);
    }
    st16(&WrTh[(long)k*262144 + (c0+tr)*512 + r0 + seg*16], hh);
    st16(&WrTl[(long)k*262144 + (c0+tr)*512 + r0 + seg*16], ll);
  }
}

__global__ __launch_bounds__(256) void k_asmT(const float* __restrict__ Fq,
    const float* __restrict__ Fr0, const float* __restrict__ Frr,
    const float* sc, const float* __restrict__ PP,
    ush* Mh, ush* Ml, ush* MTh, ush* MTl){
  __shared__ uint32 tb[64*65];
  const int z = blockIdx.z;
  const int r = threadIdx.x >> 2;
  const int cs = (threadIdx.x & 3)*16;
  const long ROFF = 1048576l, RS = 262144l;
  long r0 = (long)blockIdx.y*64, c0 = (long)blockIdx.x*64;
  const float* dsrc; const float* msrc; const float* psrc = nullptr;
  float s; long obase; long old_; float sgn;
  if (z==0){
    s = sc[0]; sgn = 1.f;
    dsrc = &Fq[(r0+r)*1024 + c0 + cs];
    msrc = &Fq[(c0+r)*1024 + r0 + cs];
    psrc = &PP[(r0+r)*1024 + c0 + cs];
    obase = 0; old_ = 1024;
  } else {
    if (blockIdx.x>=8 || blockIdx.y>=8) return;
    const int b = z-1;
    if (b==0){
      s = sc[1]; sgn = 1.f;
      dsrc = &Fr0[(r0+r)*512 + c0 + cs];
      msrc = &Fr0[(c0+r)*512 + r0 + cs];
    } else {
      s = sc[1+b]; sgn = -1.f;
      const float* W = Frr + (long)(b-1)*524288;
      dsrc = &W[(r0+r)*1024 + c0 + cs];
      msrc = &W[(c0+r)*1024 + r0 + cs];
      psrc = &PP[ROFF + (long)(b-1)*RS + (r0+r)*512 + c0 + cs];
    }
    obase = ROFF + (long)b*RS; old_ = 512;
  }
  #pragma unroll
  for (int u=0;u<16;u++) tb[r*65 + cs + u] = __float_as_uint(msrc[u]);
  __syncthreads();
  ush hh[16] __attribute__((aligned(16)));
  ush ll[16] __attribute__((aligned(16)));
  #pragma unroll
  for (int u=0;u<16;u++){
    const int c = cs + u;
    float mir = __uint_as_float(tb[c*65 + r]);
    float a = sgn * s * (dsrc[u] - mir);
    if (psrc) a += psrc[u];
    float m = ((r0 + r == c0 + c) ? 1.f : 0.f) + a;
    ush h = f2b(m); ush l = f2b(m - b2f(h));
    hh[u]=h; ll[u]=l;
  }
  st16(&Mh[obase + (r0+r)*old_ + c0 + cs], hh);
  st16(&Ml[obase + (r0+r)*old_ + c0 + cs], ll);
  __syncthreads();
  #pragma unroll
  for (int u=0;u<16;u++) tb[r*65 + cs + u] = (uint32)hh[u] | ((uint32)ll[u]<<16);
  __syncthreads();
  const int tr = threadIdx.x>>2, seg = threadIdx.x&3;
  #pragma unroll
  for (int u=0;u<16;u++){
    uint32 v = tb[(seg*16+u)*65 + tr];
    hh[u]=(ush)(v&0xffffu); ll[u]=(ush)(v>>16);
  }
  st16(&MTh[obase + (c0+tr)*old_ + r0 + seg*16], hh);
  st16(&MTl[obase + (c0+tr)*old_ + r0 + seg*16], ll);
}

__global__ __launch_bounds__(256) void k_rowabs(const float* __restrict__ T2, float* bmax){
  const int y = blockIdx.y;
  const float* row; int n;
  if (y==0){ row = T2 + (long)blockIdx.x*1024; n = 1024; }
  else { if (blockIdx.x >= 512) return;
         row = T2 + 1048576l + (long)(y-1)*262144 + (long)blockIdx.x*512; n = 512; }
  float s=0.f;
  for (int i=threadIdx.x;i<n;i+=256) s += fabsf(row[i]);
  #pragma unroll
  for (int o=32;o>0;o>>=1) s += __shfl_down(s,o,64);
  __shared__ float red[4];
  if ((threadIdx.x&63)==0) red[threadIdx.x>>6]=s;
  __syncthreads();
  if (threadIdx.x==0){
    float tot = red[0]+red[1]+red[2]+red[3];
    atomicMax((unsigned int*)&bmax[y], __float_as_uint(tot));
  }
}

__global__ void k_makec(const float* bmax, float* cvl){
  int t=threadIdx.x;
  if (t<9){
    float bnd = sqrtf(fmaxf(bmax[t], 1.f));
    cvl[t] = 1.9f/(1.f + bnd);
  }
}

__global__ __launch_bounds__(256) void k_topT(const ush* __restrict__ Xh, const ush* __restrict__ Xl,
    ush* Qb, ush* QTb, ush* RK, ush* RKT){
  __shared__ uint32 tb[64*65];
  const int z = blockIdx.z;
  const int r = threadIdx.x >> 2;
  const int cs = (threadIdx.x & 3)*16;
  const long ROFF = 1048576l, RS = 262144l;
  long r0 = (long)blockIdx.y*64, c0 = (long)blockIdx.x*64;
  ush hh[16] __attribute__((aligned(16)));
  if (z==0){
    const long base = (r0+r)*1024 + c0 + cs;
    #pragma unroll
    for (int u=0;u<16;u++){
      float v = 2.f*(b2f(Xh[base+u]) + b2f(Xl[base+u])) - ((r0+r == c0+cs+u)?1.f:0.f);
      hh[u] = f2b(v);
      tb[r*65 + cs + u] = hh[u];
    }
    st16(&Qb[(r0+r)*1024 + c0 + cs], hh);
    __syncthreads();
    const int tr = threadIdx.x>>2, seg = threadIdx.x&3;
    #pragma unroll
    for (int u=0;u<16;u++) hh[u] = (ush)tb[(seg*16+u)*65 + tr];
    st16(&QTb[(c0+tr)*4096 + r0 + seg*16], hh);
  } else {
    if (blockIdx.x>=8 || blockIdx.y>=8) return;
    const int b = z-1;
    const long base = ROFF + (long)b*RS + (r0+r)*512 + c0 + cs;
    #pragma unroll
    for (int u=0;u<16;u++){
      float v = 2.f*(b2f(Xh[base+u]) + b2f(Xl[base+u])) - ((r0+r == c0+cs+u)?1.f:0.f);
      hh[u] = f2b(v);
      tb[r*65 + cs + u] = hh[u];
    }
    st16(&RKT[(long)b*524288 + (r0+r)*512 + c0 + cs], hh);
    __syncthreads();
    const int tr = threadIdx.x>>2, seg = threadIdx.x&3;
    #pragma unroll
    for (int u=0;u<16;u++) hh[u] = (ush)tb[(seg*16+u)*65 + tr];
    st16(&RK[(long)b*524288 + (c0+tr)*1024 + r0 + seg*16], hh);
  }
}

__global__ __launch_bounds__(256) void k_f2bf(const float* __restrict__ in, ush* __restrict__ o){
  long i = ((long)blockIdx.x*256 + threadIdx.x)*8;
  float4 a = *(const float4*)(in+i);
  float4 b = *(const float4*)(in+i+4);
  ush u[8] __attribute__((aligned(16)));
  u[0]=f2b(a.x);u[1]=f2b(a.y);u[2]=f2b(a.z);u[3]=f2b(a.w);
  u[4]=f2b(b.x);u[5]=f2b(b.y);u[6]=f2b(b.z);u[7]=f2b(b.w);
  *(int4*)(o+i) = *(const int4*)u;
}

// ------------------------------ host driver -------------------------------

static GA mk(const ush* Ah, const ush* Al, long lda,
             const ush* Bh, const ush* Bl, long ldb,
             int K, int M, int N, float alpha){
  GA g{}; g.ksplit=1<<30; g.A0h=Ah; g.A0l=Al; g.lda0=lda;
  g.Bh=Bh; g.Bl=Bl; g.ldb=ldb; g.K=K; g.M=M; g.N=N; g.alpha=alpha; g.beta=0.f;
  return g;
}

extern "C" void kernel_launch(void* const* d_in, const int* in_sizes, int n_in,
                              void* d_out, int out_size, void* d_ws, size_t ws_size,
                              hipStream_t stream)
{
  (void)in_sizes; (void)n_in; (void)out_size; (void)ws_size;
  const float* x   = (const float*)d_in[0];
  const float* Fq  = (const float*)d_in[1];
  const float* fqp = (const float*)d_in[2];
  const float* by  = (const float*)d_in[3];
  const float* Fr0 = (const float*)d_in[4];
  const float* Frr = (const float*)d_in[5];
  const float* frp = (const float*)d_in[6];
  const float* bp  = (const float*)d_in[7];
  float* out = (float*)d_out;

  const float SQG = sqrtf(10.0f - 0.1f);
  const long UN = 3145728l;
  const long ROFF = 1048576l, RS = 262144l;

  char* base = (char*)d_ws;
  size_t off = 0;
  auto alloc = [&](size_t bytes)->char*{
    char* p = base + off; off = (off + bytes + 255) & ~(size_t)255; return p;
  };

  // ---- persistent ----
  ush* Qb  = (ush*)alloc(4194304l*2);
  ush* QTb = (ush*)alloc(4194304l*2);
  ush* RK  = (ush*)alloc(4194304l*2);
  ush* RKT = (ush*)alloc(4194304l*2);
  ush* xbf = (ush*)alloc(8388608l*2);
  float* scal = (float*)alloc(256*4);
  float* s2   = scal;
  float* bmax = scal + 16;
  float* cvl  = scal + 32;
  float* sc   = scal + 48;
  int*   bar  = (int*)(scal + 64);

  const size_t scratch0 = off;
  ush* Vh   = (ush*)alloc(UN*2);
  ush* Vl   = (ush*)alloc(UN*2);
  ush* Vth  = (ush*)alloc(UN*2);
  ush* Vtl  = (ush*)alloc(UN*2);
  ush* Wrh  = (ush*)alloc(1835008l*2);
  ush* Wrl  = (ush*)alloc(1835008l*2);
  ush* WrTh = (ush*)alloc(1835008l*2);
  ush* WrTl = (ush*)alloc(1835008l*2);
  float* PPf = (float*)alloc(UN*4);
  ush* Mh  = (ush*)alloc(UN*2);
  ush* Ml  = (ush*)alloc(UN*2);
  ush* MTh = (ush*)alloc(UN*2);
  ush* MTl = (ush*)alloc(UN*2);
  ush* Sh  = (ush*)alloc(UN*2);
  ush* XhA = (ush*)alloc(UN*2);
  ush* XhB = (ush*)alloc(UN*2);
  ush* XlA = (ush*)alloc(UN*2);
  ush* XlB = (ush*)alloc(UN*2);
  ush* XThA = (ush*)alloc(UN*2);
  ush* XThB = (ush*)alloc(UN*2);
  ush* XTlA = (ush*)alloc(UN*2);
  ush* XTlB = (ush*)alloc(UN*2);
  float* XfA = (float*)alloc(UN*4);
  float* XfB = (float*)alloc(UN*4);
  ush* Yh  = (ush*)alloc(UN*2);
  ush* Yl  = (ush*)alloc(UN*2);

  ush* Xh[2]  = {XhA, XhB};
  ush* Xl[2]  = {XlA, XlB};
  ush* XTh[2] = {XThA, XThB};
  ush* XTl[2] = {XTlA, XTlB};
  float* Xf[2] = {XfA, XfB};

  dim3 B256(256);
  GA ga{}, gr{};

  // ---- phase 0: norms & scales ----
  (void)hipMemsetAsync(scal, 0, 1024, stream);
  k_norms<<<dim3(64,9),B256,0,stream>>>(Fq, Fr0, Frr, s2);
  k_scales<<<1,16,0,stream>>>(s2, fqp, frp, sc);

  // ---- phase 1: build V / Wr ----
  k_buildT<<<dim3(16,48,8),B256,0,stream>>>(Fq, Frr, sc, Vh,Vl,Vth,Vtl, Wrh,Wrl,WrTh,WrTl);

  // PQ = V^T V ; PR_k = Wr Wr^T (split) -> PPf
  ga = mk(Vth,Vtl,3072, Vth,Vtl,3072, 3072,1024,1024, 1.f); ga.o0=PPf; ga.ldo0=1024;
  gr = mk(Wrh,Wrl,512, Wrh,Wrl,512, 512,512,512, 1.f);
  gr.sA=RS; gr.sB=RS; gr.o0=PPf+ROFF; gr.sO=RS; gr.ldo0=512;
  gemm_k<64,64,E_F32,true,false><<<dim3(16,16,8),B256,0,stream>>>(ga,gr,1);

  // ---- phase 2: assemble M, M^T ----
  k_asmT<<<dim3(16,16,9),B256,0,stream>>>(Fq, Fr0, Frr, sc, PPf, Mh,Ml,MTh,MTl);

  // ---- phase 3: bound: S = M*M^T (bf16), S^2 (f32), rowabs, c ----
  ga = mk(Mh,nullptr,1024, Mh,nullptr,1024, 1024,1024,1024, 1.f); ga.o0=Sh; ga.ldo0=1024;
  gr = mk(Mh+ROFF,nullptr,512, Mh+ROFF,nullptr,512, 512,512,512, 1.f);
  gr.sA=RS; gr.sB=RS; gr.o0=Sh+ROFF; gr.sO=RS; gr.ldo0=512;
  gemm_k<64,64,E_BF16,false,false><<<dim3(16,16,9),B256,0,stream>>>(ga,gr,1);

  ga = mk(Sh,nullptr,1024, Sh,nullptr,1024, 1024,1024,1024, 1.f); ga.o0=PPf; ga.ldo0=1024;
  gr = mk(Sh+ROFF,nullptr,512, Sh+ROFF,nullptr,512, 512,512,512, 1.f);
  gr.sA=RS; gr.sB=RS; gr.o0=PPf+ROFF; gr.sO=RS; gr.ldo0=512;
  gemm_k<64,64,E_F32,false,false><<<dim3(16,16,9),B256,0,stream>>>(ga,gr,1);
  k_rowabs<<<dim3(1024,9),B256,0,stream>>>(PPf, bmax);
  k_makec<<<1,16,0,stream>>>(bmax, cvl);

  // ---- phase 4: NS mega-kernel (initX + 9 coupled iters + promote) ----
  {
    NSA na{};
    na.Mh=Mh; na.MTh=MTh;
    na.XA=Xh[0]; na.XTA=XTh[0]; na.XB=Xh[1]; na.XTB=XTh[1];
    na.Y=Yh;
    na.Xf=Xf[1]; na.Xl=Xl[1]; na.XTl=XTl[1];
    na.cvl=cvl; na.bar=bar;
    ns_mega<<<768,B256,0,stream>>>(na);
  }
  int cur = 1;   // 9 iterations: final X in buffer-set 1

  // ---- phase 5: 2 split-precision NS iters ----
  for (int it=0; it<2; ++it){
    int nxt = cur^1;
    ga = mk(XTh[cur],XTl[cur],1024, Mh,Ml,1024, 1024,1024,1024, 1.f);
    ga.o1=Yh; ga.o2=Yl; ga.ldo0=1024;
    gr = mk(XTh[cur]+ROFF,XTl[cur]+ROFF,512, Mh+ROFF,Ml+ROFF,512, 512,512,512, 1.f);
    gr.sA=RS; gr.sB=RS; gr.o1=Yh+ROFF; gr.o2=Yl+ROFF; gr.sO=RS; gr.ldo0=512;
    gemm_k<64,64,E_SPLIT,true,false><<<dim3(16,16,9),B256,0,stream>>>(ga,gr,1);

    ga = mk(Xh[cur],Xl[cur],1024, Yh,Yl,1024, 1024,1024,1024, -1.f);
    ga.beta=2.f; ga.e0=Xf[cur];
    ga.o0=Xf[nxt]; ga.o1=Xh[nxt]; ga.o2=Xl[nxt]; ga.o3=XTh[nxt]; ga.o4=XTl[nxt];
    ga.ldo0=1024; ga.ldo1=1024;
    gr = mk(Xh[cur]+ROFF,Xl[cur]+ROFF,512, Yh+ROFF,Yl+ROFF,512, 512,512,512, -1.f);
    gr.beta=2.f; gr.e0=Xf[cur]+ROFF; gr.sD=RS;
    gr.sA=RS; gr.sB=RS; gr.sO=RS;
    gr.o0=Xf[nxt]+ROFF; gr.o1=Xh[nxt]+ROFF; gr.o2=Xl[nxt]+ROFF;
    gr.o3=XTh[nxt]+ROFF; gr.o4=XTl[nxt]+ROFF;
    gr.ldo0=512; gr.ldo1=512;
    gemm_k<64,64,E_SPLIT,true,true><<<dim3(16,16,9),B256,0,stream>>>(ga,gr,1);
    cur = nxt;
  }  // cur == 1

  // ---- phase 6: tops = 2X - I ; bottoms = -2*V*X ----
  k_topT<<<dim3(16,16,9),B256,0,stream>>>(Xh[cur], Xl[cur], Qb, QTb, RK, RKT);

  ga = mk(Vh,Vl,1024, XTh[cur],XTl[cur],1024, 1024,3072,1024, -2.f);
  ga.o0=Qb + 1048576l; ga.ldo0=1024; ga.o1=QTb + 1024; ga.ldo1=4096;
  gr = mk(WrTh,WrTl,512, XTh[cur]+ROFF+RS, XTl[cur]+ROFF+RS, 512, 512,512,512, -2.f);
  gr.sA=RS; gr.sB=RS; gr.sO=524288;
  gr.o0=RKT + 524288 + 262144; gr.ldo0=512;
  gr.o1=RK + 524288 + 512; gr.ldo1=1024;
  gemm_k<64,64,E_QW,true,true><<<dim3(16,48,8),B256,0,stream>>>(ga,gr,1);

  // ---- main-path overlay buffers ----
  off = scratch0;
  ush* xh  = (ush*)alloc(33554432l*2);
  ush* yh  = (ush*)alloc(33554432l*2);

  // ---- phase 7: main chain ----
  k_f2bf<<<4096,B256,0,stream>>>(x, xbf);
  ga = mk(xbf,nullptr,1024, Qb,nullptr,1024, 1024,8192,4096, SQG);
  ga.o0=xh; ga.ldo0=4096;
  gemm_k<128,128,E_BF16,false,false><<<dim3(32,64,1),B256,0,stream>>>(ga,ga,1);

  chain_k<<<256,512,0,stream>>>(xh, RK, RKT, bp, yh);

  // out = 0.5*(10.1*x + sqrt_gam*(yh@Q)) + by
  ga = mk(yh,nullptr,4096, QTb,nullptr,4096, 4096,8192,1024, SQG);
  ga.e0=x; ga.e1=by; ga.o0=out; ga.ldo0=1024;
  gemm_k<128,128,E_OUT,false,false><<<dim3(8,64,1),B256,0,stream>>>(ga,ga,1);
}